// Round 1
// baseline (812.986 us; speedup 1.0000x reference)
//
#include <hip/hip_runtime.h>

// ---------- types ----------
typedef __bf16 bf16x8 __attribute__((ext_vector_type(8)));
typedef float  floatx4 __attribute__((ext_vector_type(4)));

__device__ __forceinline__ unsigned short f2b(float f) {
  union { float f; unsigned int u; } v; v.f = f;
  unsigned int r = v.u + 0x7FFFu + ((v.u >> 16) & 1u);  // RNE, finite inputs
  return (unsigned short)(r >> 16);
}
__device__ __forceinline__ float b2f(unsigned short h) {
  union { unsigned int u; float f; } v; v.u = ((unsigned int)h) << 16;
  return v.f;
}

// ---------- conv_w fp32 -> bf16 bits (16,777,216 elems = 4,194,304 float4) ----------
__global__ __launch_bounds__(256) void cvt_w_kernel(const float* __restrict__ w,
                                                    unsigned short* __restrict__ wb) {
  int i = blockIdx.x * 256 + threadIdx.x;
  float4 v = ((const float4*)w)[i];
  ushort4 h; h.x = f2b(v.x); h.y = f2b(v.y); h.z = f2b(v.z); h.w = f2b(v.w);
  ((ushort4*)wb)[i] = h;
}

// ---------- gather emb = item_emb[seq] -> fp32 + bf16 copies ----------
__global__ __launch_bounds__(64) void gather_kernel(const int* __restrict__ seq,
                                                    const float* __restrict__ item_emb,
                                                    float* __restrict__ ef,
                                                    unsigned short* __restrict__ eb) {
  int row = blockIdx.x;       // b*16 + t, 8192 rows
  int c4  = threadIdx.x;      // one float4 per thread (64*4 = 256)
  int idx = seq[row];
  float4 v = ((const float4*)(item_emb + (size_t)idx * 256))[c4];
  ((float4*)(ef + (size_t)row * 256))[c4] = v;
  ushort4 h; h.x = f2b(v.x); h.y = f2b(v.y); h.z = f2b(v.z); h.w = f2b(v.w);
  ((ushort4*)(eb + (size_t)row * 256))[c4] = h;
}

// ---------- fused conv-GEMM (bf16 MFMA) + sigmoid(relu) gate + 3x fo-pool scan ----------
// Grid: (64 M-tiles) x (32 N-tiles). Block 256 = 4 waves (2x2 of 64x64).
// M-tile = 8 b x 16 t (full T). N-tile = one l, 128 channels. K = (m,d), BK=64 (single m).
__global__ __launch_bounds__(256, 2) void conv_qrnn_kernel(
    const unsigned short* __restrict__ Abf,   // emb bf16 [B*T][256]
    const unsigned short* __restrict__ Wbf,   // conv_w bf16 [l][m][c][d]
    const float* __restrict__ embf,           // emb fp32 [B*T][256]
    const float* __restrict__ conv_b,         // [L][D]
    float* __restrict__ o)                    // [B][D], pre-zeroed, atomicAdd
{
  __shared__ union {
    struct { unsigned short A[128][64]; unsigned short Bm[128][64]; } st; // 32 KB staging
    unsigned short fT[128][128];                                          // 32 KB gate tile
  } sm;

  const int tid  = threadIdx.x;
  const int lane = tid & 63;
  const int wave = tid >> 6;
  const int wm   = wave >> 1;   // 0..1
  const int wn   = wave & 1;    // 0..1
  const int lrow = lane & 15;
  const int kq   = lane >> 4;   // 0..3
  const int bm   = blockIdx.x;  // 64
  const int bn   = blockIdx.y;  // 32
  const int l    = bn >> 1;
  const int c0   = (bn & 1) << 7;

  floatx4 acc[4][4];
  #pragma unroll
  for (int i = 0; i < 4; ++i)
    #pragma unroll
    for (int j = 0; j < 4; ++j)
      acc[i][j] = floatx4{0.f, 0.f, 0.f, 0.f};

  for (int kt = 0; kt < 64; ++kt) {
    const int m  = kt >> 2;          // conv tap (single per K-tile since 64 | 256)
    const int d0 = (kt & 3) << 6;    // d offset within tap
    // ---- stage A: A[(b,t)][(m,d)] = emb[b][t-m][d], zero rows for t<m ----
    #pragma unroll
    for (int it = 0; it < 4; ++it) {
      int chunk = it * 256 + tid;     // 1024 chunks of 8 bf16
      int row = chunk >> 3;
      int ch  = chunk & 7;
      int t = row & 15;
      int4 v = make_int4(0, 0, 0, 0);
      if (t >= m) {
        int grow = (bm * 8 + (row >> 4)) * 16 + (t - m);
        v = *(const int4*)(Abf + grow * 256 + d0 + ch * 8);
      }
      *(int4*)(&sm.st.A[row][ch * 8]) = v;
    }
    // ---- stage B: Bs[n=c][k=d] = conv_w[l][m][c0+n][d0+k] (contiguous in d) ----
    #pragma unroll
    for (int it = 0; it < 4; ++it) {
      int chunk = it * 256 + tid;
      int row = chunk >> 3;
      int ch  = chunk & 7;
      *(int4*)(&sm.st.Bm[row][ch * 8]) =
          *(const int4*)(Wbf + (((l * 16 + m) * 256) + (c0 + row)) * 256 + d0 + ch * 8);
    }
    __syncthreads();
    #pragma unroll
    for (int ks = 0; ks < 2; ++ks) {
      bf16x8 aF[4], bF[4];
      #pragma unroll
      for (int i = 0; i < 4; ++i)
        aF[i] = *(const bf16x8*)(&sm.st.A[wm * 64 + i * 16 + lrow][ks * 32 + kq * 8]);
      #pragma unroll
      for (int j = 0; j < 4; ++j)
        bF[j] = *(const bf16x8*)(&sm.st.Bm[wn * 64 + j * 16 + lrow][ks * 32 + kq * 8]);
      #pragma unroll
      for (int i = 0; i < 4; ++i)
        #pragma unroll
        for (int j = 0; j < 4; ++j)
          acc[i][j] = __builtin_amdgcn_mfma_f32_16x16x32_bf16(aF[i], bF[j], acc[i][j], 0, 0, 0);
    }
    __syncthreads();
  }

  // ---- epilogue: f = sigmoid(relu(acc + conv_b)) -> bf16 tile in LDS ----
  // C/D layout: col = lane&15, row = (lane>>4)*4 + reg
  #pragma unroll
  for (int j = 0; j < 4; ++j) {
    int col = wn * 64 + j * 16 + lrow;
    float cb = conv_b[l * 256 + c0 + col];
    #pragma unroll
    for (int i = 0; i < 4; ++i) {
      #pragma unroll
      for (int r = 0; r < 4; ++r) {
        int row = wm * 64 + i * 16 + kq * 4 + r;
        float x = acc[i][j][r] + cb;
        x = fmaxf(x, 0.f);
        float f = 1.f / (1.f + __expf(-x));
        sm.fT[row][col] = f2b(f);
      }
    }
  }
  __syncthreads();

  // ---- 3x fo-pooling scan over t, sum over t, accumulate into o[b][c] ----
  #pragma unroll
  for (int q = 0; q < 4; ++q) {
    int p   = q * 256 + tid;       // 1024 (b,c) pairs: 8 b x 128 c
    int c_l = p & 127;
    int b_l = p >> 7;
    int b_g = bm * 8 + b_l;
    int c   = c0 + c_l;
    float xv[16], fv[16];
    #pragma unroll
    for (int t = 0; t < 16; ++t) {
      xv[t] = embf[(b_g * 16 + t) * 256 + c];
      fv[t] = b2f(sm.fT[b_l * 16 + t][c_l]);
    }
    #pragma unroll
    for (int pass = 0; pass < 3; ++pass) {
      float h = 0.f;
      #pragma unroll
      for (int t = 0; t < 16; ++t) { h = fv[t] * xv[t] + (1.f - fv[t]) * h; xv[t] = h; }
    }
    float s = 0.f;
    #pragma unroll
    for (int t = 0; t < 16; ++t) s += xv[t];
    atomicAdd(&o[b_g * 256 + c], s);
  }
}

// ---------- head: z = [o, user_emb[user]] @ fc1_w.T + fc1_b; res = z . W2[item] + b2 ----------
__global__ __launch_bounds__(256) void head_kernel(
    const float* __restrict__ o, const float* __restrict__ user_emb,
    const int* __restrict__ user_var, const float* __restrict__ fc1_w,
    const float* __restrict__ fc1_b, const float* __restrict__ W2,
    const float* __restrict__ b2, const int* __restrict__ item_var,
    float* __restrict__ out)
{
  __shared__ __align__(16) float cat[512];
  __shared__ __align__(16) float zz[256];
  int b = blockIdx.x;
  int tid = threadIdx.x;
  int uid = user_var[b];
  cat[tid]       = o[b * 256 + tid];
  cat[256 + tid] = user_emb[(size_t)uid * 256 + tid];
  __syncthreads();
  float a = fc1_b[tid];
  const float4* wr = (const float4*)(fc1_w + tid * 512);  // fc1_w[j][k], j=tid
  #pragma unroll 4
  for (int k4 = 0; k4 < 128; ++k4) {
    float4 w4 = wr[k4];
    a += w4.x * cat[k4 * 4] + w4.y * cat[k4 * 4 + 1] + w4.z * cat[k4 * 4 + 2] + w4.w * cat[k4 * 4 + 3];
  }
  zz[tid] = a;
  __syncthreads();
  int n = tid >> 3, s = tid & 7;                 // 32 targets x 8 lanes
  int it = item_var[b * 32 + n];
  const float4* w   = (const float4*)(W2 + (size_t)it * 256);
  const float4* zv4 = (const float4*)zz;
  float acc = 0.f;
  #pragma unroll
  for (int i = 0; i < 8; ++i) {
    int k4 = i * 8 + s;                          // lanes read consecutive float4s
    float4 wv = w[k4];
    float4 zv = zv4[k4];
    acc += wv.x * zv.x + wv.y * zv.y + wv.z * zv.z + wv.w * zv.w;
  }
  acc += __shfl_down(acc, 4, 8);
  acc += __shfl_down(acc, 2, 8);
  acc += __shfl_down(acc, 1, 8);
  if (s == 0) out[b * 32 + n] = acc + b2[it];
}

extern "C" void kernel_launch(void* const* d_in, const int* in_sizes, int n_in,
                              void* d_out, int out_size, void* d_ws, size_t ws_size,
                              hipStream_t stream) {
  (void)in_sizes; (void)n_in; (void)out_size; (void)ws_size;
  const int*   seq_var  = (const int*)d_in[0];
  const int*   user_var = (const int*)d_in[1];
  const int*   item_var = (const int*)d_in[2];
  const float* item_emb = (const float*)d_in[3];
  const float* user_emb = (const float*)d_in[4];
  const float* conv_w   = (const float*)d_in[5];
  const float* conv_b   = (const float*)d_in[6];
  const float* fc1_w    = (const float*)d_in[7];
  const float* fc1_b    = (const float*)d_in[8];
  const float* W2       = (const float*)d_in[9];
  const float* b2       = (const float*)d_in[10];
  float* out = (float*)d_out;

  char* ws = (char*)d_ws;
  unsigned short* cwb = (unsigned short*)ws;                          // 33,554,432 B
  unsigned short* ebf = (unsigned short*)(ws + 33554432);             //  4,194,304 B
  float*          ef  = (float*)(ws + 33554432 + 4194304);            //  8,388,608 B
  float*          o   = (float*)(ws + 33554432 + 4194304 + 8388608);  //    524,288 B

  hipMemsetAsync(o, 0, 512 * 256 * sizeof(float), stream);
  cvt_w_kernel<<<16384, 256, 0, stream>>>(conv_w, cwb);
  gather_kernel<<<8192, 64, 0, stream>>>(seq_var, item_emb, ef, ebf);
  dim3 grid(64, 32);
  conv_qrnn_kernel<<<grid, 256, 0, stream>>>(ebf, cwb, ef, conv_b, o);
  head_kernel<<<512, 256, 0, stream>>>(o, user_emb, user_var, fc1_w, fc1_b, W2, b2, item_var, out);
}

// Round 2
// 597.448 us; speedup vs baseline: 1.3608x; 1.3608x over previous
//
#include <hip/hip_runtime.h>

// ---------- types ----------
typedef __bf16 bf16x8 __attribute__((ext_vector_type(8)));
typedef float  floatx4 __attribute__((ext_vector_type(4)));

__device__ __forceinline__ unsigned short f2b(float f) {
  union { float f; unsigned int u; } v; v.f = f;
  unsigned int r = v.u + 0x7FFFu + ((v.u >> 16) & 1u);  // RNE, finite inputs
  return (unsigned short)(r >> 16);
}
__device__ __forceinline__ float b2f(unsigned short h) {
  union { unsigned int u; float f; } v; v.u = ((unsigned int)h) << 16;
  return v.f;
}
// async global->LDS, 16B per lane; LDS dest must be wave-uniform base + lane*16
__device__ __forceinline__ void gld16(const void* g, void* l) {
  __builtin_amdgcn_global_load_lds(
      (const __attribute__((address_space(1))) unsigned int*)g,
      (__attribute__((address_space(3))) unsigned int*)l, 16, 0, 0);
}

// ---------- conv_w fp32 -> bf16, reordered [l][h][kt][c_l][chunk^(c_l&7)], triangular m<=l ----------
__global__ __launch_bounds__(256) void cvt_w_kernel(const float* __restrict__ w,
                                                    unsigned short* __restrict__ wr) {
  int gid = blockIdx.x * 256 + threadIdx.x;   // 2,097,152 chunks of 8 floats
  int dc = gid & 31;           // d-chunk (8 d each)
  int c  = (gid >> 5) & 255;
  int m  = (gid >> 13) & 15;
  int l  = gid >> 17;
  if (m > l) return;           // structural zeros — never read (K-loop skips m>l)
  const float4* src = (const float4*)(w + (size_t)gid * 8);
  float4 v0 = src[0], v1 = src[1];
  ushort4 h0, h1;
  h0.x = f2b(v0.x); h0.y = f2b(v0.y); h0.z = f2b(v0.z); h0.w = f2b(v0.w);
  h1.x = f2b(v1.x); h1.y = f2b(v1.y); h1.z = f2b(v1.z); h1.w = f2b(v1.w);
  int hh = c >> 7, cl = c & 127;
  int kt = m * 4 + (dc >> 3);
  int phys = (dc & 7) ^ (cl & 7);   // bake the LDS bank swizzle into the layout
  size_t off = (((size_t)(l * 2 + hh) * 64 + (size_t)kt) * 128 + cl) * 64 + phys * 8;
  *(ushort4*)(wr + off)     = h0;
  *(ushort4*)(wr + off + 4) = h1;
}

// ---------- gather emb = item_emb[seq] -> fp32 (linear) + bf16 (chunk-swizzled by t&7) ----------
__global__ __launch_bounds__(64) void gather_kernel(const int* __restrict__ seq,
                                                    const float* __restrict__ item_emb,
                                                    float* __restrict__ ef,
                                                    unsigned short* __restrict__ eb) {
  int row = blockIdx.x;       // b*16 + t
  int c4  = threadIdx.x;      // half-chunk (4 elems)
  int t   = row & 15;
  int idx = seq[row];
  float4 v = ((const float4*)(item_emb + (size_t)idx * 256))[c4];
  ((float4*)(ef + (size_t)row * 256))[c4] = v;
  ushort4 h; h.x = f2b(v.x); h.y = f2b(v.y); h.z = f2b(v.z); h.w = f2b(v.w);
  int j = c4 >> 1, half = c4 & 1;
  int pp = (((j ^ (t & 7)) & 7) | (j & 24)) * 2 + half;   // swizzle low 3 bits of chunk idx
  ((ushort4*)(eb + (size_t)row * 256))[pp] = h;
}

// ---------- fused conv-GEMM (bf16 MFMA) + gate + 3x fo-pool scan ----------
// 1D grid 2048: l = 15 - bid/128 (heavy blocks first), sub = bid%128 -> bm (64), half (2).
// Block tile 128(M=8b x 16t) x 128(N=c). K-loop: (l+1)*4 tiles of BK=64 (triangular skip).
// A and B staged via global_load_lds width-16 from pre-swizzled ws arrays.
__global__ __launch_bounds__(256, 4) void conv_qrnn_kernel(
    const unsigned short* __restrict__ Abf,   // pre-swizzled emb bf16 [8192][256]
    const unsigned short* __restrict__ Wr,    // reordered conv_w bf16
    const float* __restrict__ embf,           // emb fp32 [8192][256] (linear)
    const float* __restrict__ conv_b,         // [16][256]
    const char* __restrict__ zp,              // 512 B of zeros
    float* __restrict__ o)                    // [512][256], pre-zeroed, atomicAdd
{
  __shared__ union {
    struct { unsigned short A[128 * 64]; unsigned short B[128 * 64]; } st; // 2x16 KB
    unsigned short fT[128 * 128];                                          // 32 KB
  } sm;

  const int tid  = threadIdx.x;
  const int lane = tid & 63;
  const int wave = tid >> 6;
  const int wm   = wave >> 1;   // 0..1
  const int wn   = wave & 1;    // 0..1
  const int lrow = lane & 15;
  const int kq   = lane >> 4;   // 0..3

  const int bid = blockIdx.x;
  const int l   = 15 - (bid >> 7);    // heavy (long-K) blocks dispatch first
  const int sub = bid & 127;
  const int bm  = sub >> 1;
  const int c0  = (sub & 1) << 7;

  // A-staging per-thread constants: 4 issues share t & chunk; b differs by it*2
  const int tA = (tid >> 3) & 15;     // source t for all 4 issues
  const int bh = tid >> 7;            // 0..1
  const int ck = tid & 7;             // 16B chunk within 128B row-window
  const char* const AbfB = (const char*)Abf;
  const size_t gb0 = ((size_t)(bm * 8 + bh) * 16 + tA) * 512 + (size_t)ck * 16;
  const char* const WrB = (const char*)Wr + (size_t)((l * 2) + (sub & 1)) * 64 * 16384;

  floatx4 acc[4][4];
  #pragma unroll
  for (int i = 0; i < 4; ++i)
    #pragma unroll
    for (int j = 0; j < 4; ++j)
      acc[i][j] = floatx4{0.f, 0.f, 0.f, 0.f};

  for (int m = 0; m <= l; ++m) {
    const char* srcA[4];
    {
      const bool valid = (tA >= m);
      const size_t base = gb0 - (size_t)m * 512;
      #pragma unroll
      for (int it = 0; it < 4; ++it)
        srcA[it] = valid ? (AbfB + base + (size_t)it * 16384) : (zp + ck * 16);
    }
    const int swzA = (lrow - m) & 7;
    for (int db = 0; db < 4; ++db) {
      const int kt = m * 4 + db;
      // stage A: 16 KB (zero rows come from the zero page)
      #pragma unroll
      for (int it = 0; it < 4; ++it)
        gld16(srcA[it] + db * 128, (char*)sm.st.A + ((size_t)(it * 256 + tid)) * 16);
      // stage B: contiguous 16 KB tile
      const char* wsrc = WrB + (size_t)kt * 16384;
      #pragma unroll
      for (int it = 0; it < 4; ++it)
        gld16(wsrc + (size_t)(it * 256 + tid) * 16, (char*)sm.st.B + ((size_t)(it * 256 + tid)) * 16);
      __syncthreads();
      #pragma unroll
      for (int ks = 0; ks < 2; ++ks) {
        const int pa = (((ks * 4 + kq) ^ swzA) & 7) * 8;
        const int pb = (((ks * 4 + kq) ^ lrow) & 7) * 8;
        bf16x8 aF[4], bF[4];
        #pragma unroll
        for (int i = 0; i < 4; ++i)
          aF[i] = *(const bf16x8*)&sm.st.A[(wm * 64 + i * 16 + lrow) * 64 + pa];
        #pragma unroll
        for (int j = 0; j < 4; ++j)
          bF[j] = *(const bf16x8*)&sm.st.B[(wn * 64 + j * 16 + lrow) * 64 + pb];
        #pragma unroll
        for (int i = 0; i < 4; ++i)
          #pragma unroll
          for (int j = 0; j < 4; ++j)
            acc[i][j] = __builtin_amdgcn_mfma_f32_16x16x32_bf16(aF[i], bF[j], acc[i][j], 0, 0, 0);
      }
      __syncthreads();
    }
  }

  // ---- epilogue: f = sigmoid(relu(acc + conv_b)) -> bf16 tile in LDS ----
  // C/D layout: col = lane&15, row = (lane>>4)*4 + reg
  #pragma unroll
  for (int j = 0; j < 4; ++j) {
    int col = wn * 64 + j * 16 + lrow;
    float cb = conv_b[l * 256 + c0 + col];
    #pragma unroll
    for (int i = 0; i < 4; ++i) {
      #pragma unroll
      for (int r = 0; r < 4; ++r) {
        int row = wm * 64 + i * 16 + kq * 4 + r;
        float x = acc[i][j][r] + cb;
        x = fmaxf(x, 0.f);
        float f = 1.f / (1.f + __expf(-x));
        sm.fT[row * 128 + col] = f2b(f);
      }
    }
  }
  __syncthreads();

  // ---- 3x fo-pooling scan over t, sum over t, accumulate into o[b][c] ----
  #pragma unroll
  for (int q = 0; q < 4; ++q) {
    int p   = q * 256 + tid;       // 1024 (b,c) pairs: 8 b x 128 c
    int c_l = p & 127;
    int b_l = p >> 7;
    int b_g = bm * 8 + b_l;
    int c   = c0 + c_l;
    float xv[16], fv[16];
    #pragma unroll
    for (int t = 0; t < 16; ++t) {
      xv[t] = embf[((size_t)b_g * 16 + t) * 256 + c];
      fv[t] = b2f(sm.fT[(b_l * 16 + t) * 128 + c_l]);
    }
    #pragma unroll
    for (int pass = 0; pass < 3; ++pass) {
      float h = 0.f;
      #pragma unroll
      for (int t = 0; t < 16; ++t) { h = fv[t] * xv[t] + (1.f - fv[t]) * h; xv[t] = h; }
    }
    float s = 0.f;
    #pragma unroll
    for (int t = 0; t < 16; ++t) s += xv[t];
    atomicAdd(&o[b_g * 256 + c], s);
  }
}

// ---------- head: z = [o, user_emb[user]] @ fc1_w.T + fc1_b; res = z . W2[item] + b2 ----------
__global__ __launch_bounds__(256) void head_kernel(
    const float* __restrict__ o, const float* __restrict__ user_emb,
    const int* __restrict__ user_var, const float* __restrict__ fc1_w,
    const float* __restrict__ fc1_b, const float* __restrict__ W2,
    const float* __restrict__ b2, const int* __restrict__ item_var,
    float* __restrict__ out)
{
  __shared__ __align__(16) float cat[512];
  __shared__ __align__(16) float zz[256];
  int b = blockIdx.x;
  int tid = threadIdx.x;
  int uid = user_var[b];
  cat[tid]       = o[b * 256 + tid];
  cat[256 + tid] = user_emb[(size_t)uid * 256 + tid];
  __syncthreads();
  float a = fc1_b[tid];
  const float4* wr = (const float4*)(fc1_w + tid * 512);
  #pragma unroll 4
  for (int k4 = 0; k4 < 128; ++k4) {
    float4 w4 = wr[k4];
    a += w4.x * cat[k4 * 4] + w4.y * cat[k4 * 4 + 1] + w4.z * cat[k4 * 4 + 2] + w4.w * cat[k4 * 4 + 3];
  }
  zz[tid] = a;
  __syncthreads();
  int n = tid >> 3, s = tid & 7;
  int it = item_var[b * 32 + n];
  const float4* w   = (const float4*)(W2 + (size_t)it * 256);
  const float4* zv4 = (const float4*)zz;
  float acc = 0.f;
  #pragma unroll
  for (int i = 0; i < 8; ++i) {
    int k4 = i * 8 + s;
    float4 wv = w[k4];
    float4 zv = zv4[k4];
    acc += wv.x * zv.x + wv.y * zv.y + wv.z * zv.z + wv.w * zv.w;
  }
  acc += __shfl_down(acc, 4, 8);
  acc += __shfl_down(acc, 2, 8);
  acc += __shfl_down(acc, 1, 8);
  if (s == 0) out[b * 32 + n] = acc + b2[it];
}

extern "C" void kernel_launch(void* const* d_in, const int* in_sizes, int n_in,
                              void* d_out, int out_size, void* d_ws, size_t ws_size,
                              hipStream_t stream) {
  (void)in_sizes; (void)n_in; (void)out_size; (void)ws_size;
  const int*   seq_var  = (const int*)d_in[0];
  const int*   user_var = (const int*)d_in[1];
  const int*   item_var = (const int*)d_in[2];
  const float* item_emb = (const float*)d_in[3];
  const float* user_emb = (const float*)d_in[4];
  const float* conv_w   = (const float*)d_in[5];
  const float* conv_b   = (const float*)d_in[6];
  const float* fc1_w    = (const float*)d_in[7];
  const float* fc1_b    = (const float*)d_in[8];
  const float* W2       = (const float*)d_in[9];
  const float* b2       = (const float*)d_in[10];
  float* out = (float*)d_out;

  char* ws = (char*)d_ws;
  unsigned short* cwr = (unsigned short*)ws;                          // 33,554,432 B
  unsigned short* ebf = (unsigned short*)(ws + 33554432);             //  4,194,304 B
  float*          ef  = (float*)(ws + 33554432 + 4194304);            //  8,388,608 B
  float*          o   = (float*)(ws + 33554432 + 4194304 + 8388608);  //    524,288 B
  char*           zp  = ws + 33554432 + 4194304 + 8388608 + 524288;   //        512 B

  hipMemsetAsync(o, 0, 524288 + 512, stream);   // zeros o and the zero page
  cvt_w_kernel<<<8192, 256, 0, stream>>>(conv_w, cwr);
  gather_kernel<<<8192, 64, 0, stream>>>(seq_var, item_emb, ef, ebf);
  conv_qrnn_kernel<<<2048, 256, 0, stream>>>(ebf, cwr, ef, conv_b, zp, o);
  head_kernel<<<512, 256, 0, stream>>>(o, user_emb, user_var, fc1_w, fc1_b, W2, b2, item_var, out);
}

// Round 3
// 569.074 us; speedup vs baseline: 1.4286x; 1.0499x over previous
//
#include <hip/hip_runtime.h>

// ---------- types ----------
typedef __bf16 bf16x8 __attribute__((ext_vector_type(8)));
typedef float  floatx4 __attribute__((ext_vector_type(4)));

__device__ __forceinline__ unsigned short f2b(float f) {
  union { float f; unsigned int u; } v; v.f = f;
  unsigned int r = v.u + 0x7FFFu + ((v.u >> 16) & 1u);  // RNE, finite inputs
  return (unsigned short)(r >> 16);
}
__device__ __forceinline__ float b2f(unsigned short h) {
  union { unsigned int u; float f; } v; v.u = ((unsigned int)h) << 16;
  return v.f;
}
// async global->LDS, 16B per lane; LDS dest must be wave-uniform base + lane*16
__device__ __forceinline__ void gld16(const void* g, void* l) {
  __builtin_amdgcn_global_load_lds(
      (const __attribute__((address_space(1))) unsigned int*)g,
      (__attribute__((address_space(3))) unsigned int*)l, 16, 0, 0);
}

// ---------- prep: conv_w cvt+reorder | emb gather | fc1_w transpose ----------
// bid <  8192 : conv_w fp32 -> bf16, layout [l][kt][c][chunk^(c&7)], triangular m<=l
// bid < 10240 : gather emb -> fp32 (linear) + bf16 (chunk-swizzled by t&7)
// else (32)   : transpose fc1_w [256][512] -> fwT [512][256]
__global__ __launch_bounds__(256) void prep_kernel(
    const float* __restrict__ w, unsigned short* __restrict__ wr,
    const int* __restrict__ seq, const float* __restrict__ item_emb,
    float* __restrict__ ef, unsigned short* __restrict__ eb,
    const float* __restrict__ fc1_w, float* __restrict__ fwT)
{
  __shared__ float tl[64][65];
  const int bid = blockIdx.x, tid = threadIdx.x;
  if (bid < 8192) {
    int gid = bid * 256 + tid;          // 2,097,152 chunks of 8 floats
    int dc = gid & 31;                  // d-chunk (8 d each)
    int c  = (gid >> 5) & 255;
    int m  = (gid >> 13) & 15;
    int l  = gid >> 17;
    if (m > l) return;                  // structural zeros — never read
    const float4* src = (const float4*)(w + (size_t)gid * 8);
    float4 v0 = src[0], v1 = src[1];
    ushort4 h0, h1;
    h0.x = f2b(v0.x); h0.y = f2b(v0.y); h0.z = f2b(v0.z); h0.w = f2b(v0.w);
    h1.x = f2b(v1.x); h1.y = f2b(v1.y); h1.z = f2b(v1.z); h1.w = f2b(v1.w);
    int kt = m * 4 + (dc >> 3);
    int phys = (dc & 7) ^ (c & 7);      // bake the LDS bank swizzle into the layout
    size_t off = (((size_t)(l * 64 + kt)) * 256 + c) * 64 + phys * 8;
    *(ushort4*)(wr + off)     = h0;
    *(ushort4*)(wr + off + 4) = h1;
  } else if (bid < 10240) {
    int row = (bid - 8192) * 4 + (tid >> 6);   // b*16 + t
    int c4  = tid & 63;
    int t   = row & 15;
    int idx = seq[row];
    float4 v = ((const float4*)(item_emb + (size_t)idx * 256))[c4];
    ((float4*)(ef + (size_t)row * 256))[c4] = v;
    ushort4 h; h.x = f2b(v.x); h.y = f2b(v.y); h.z = f2b(v.z); h.w = f2b(v.w);
    int j = c4 >> 1, half = c4 & 1;
    int pp = (((j ^ (t & 7)) & 7) | (j & 24)) * 2 + half;
    ((ushort4*)(eb + (size_t)row * 256))[pp] = h;
  } else {
    int tb = bid - 10240;               // 32 tiles: 4 (j) x 8 (k)
    int j0 = (tb >> 3) * 64, k0 = (tb & 7) * 64;
    #pragma unroll
    for (int it = 0; it < 4; ++it) {
      int q = it * 256 + tid, j = q >> 4, k4 = q & 15;
      float4 v = *(const float4*)(fc1_w + (size_t)(j0 + j) * 512 + k0 + k4 * 4);
      tl[j][k4 * 4 + 0] = v.x; tl[j][k4 * 4 + 1] = v.y;
      tl[j][k4 * 4 + 2] = v.z; tl[j][k4 * 4 + 3] = v.w;
    }
    __syncthreads();
    #pragma unroll
    for (int it = 0; it < 4; ++it) {
      int q = it * 256 + tid, k = q >> 4, j4 = q & 15;
      float4 v = { tl[j4 * 4 + 0][k], tl[j4 * 4 + 1][k],
                   tl[j4 * 4 + 2][k], tl[j4 * 4 + 3][k] };
      *(float4*)(fwT + (size_t)(k0 + k) * 256 + j0 + j4 * 4) = v;
    }
  }
}

// ---------- fused conv-GEMM (bf16 MFMA) + gate + 3x fo-pool scan ----------
// Grid 1024: l = 15 - bid/64 (heavy first), bm = bid%64.
// Block tile 128(M=8b x 16t) x 256(N=c, full l). 4 waves 2x2, wave tile 64x128.
// K-loop: (l+1)*4 tiles of BK=64 (triangular skip). Staging via global_load_lds.
__global__ __launch_bounds__(256, 2) void conv_qrnn_kernel(
    const unsigned short* __restrict__ Abf,   // pre-swizzled emb bf16 [8192][256]
    const unsigned short* __restrict__ Wr,    // reordered conv_w bf16
    const float* __restrict__ embf,           // emb fp32 [8192][256] (linear)
    const float* __restrict__ conv_b,         // [16][256]
    const char* __restrict__ zp,              // 512 B of zeros
    float* __restrict__ o)                    // [512][256], pre-zeroed, atomicAdd
{
  __shared__ union {
    struct { unsigned short A[128 * 64]; unsigned short B[256 * 64]; } st; // 16+32 KB
    unsigned short fT[128 * 256];                                          // 64 KB
  } sm;

  const int tid  = threadIdx.x;
  const int lane = tid & 63;
  const int wave = tid >> 6;
  const int wm   = wave >> 1;   // 0..1 (M)
  const int wn   = wave & 1;    // 0..1 (N, 128 each)
  const int lrow = lane & 15;
  const int kq   = lane >> 4;   // 0..3

  const int bid = blockIdx.x;
  const int l   = 15 - (bid >> 6);    // heavy (long-K) blocks dispatch first
  const int bm  = bid & 63;

  const int tA = (tid >> 3) & 15;     // source t for all 4 A-issues
  const int bh = tid >> 7;            // 0..1
  const int ck = tid & 7;             // 16B chunk within 128B row-window
  const char* const AbfB = (const char*)Abf;
  const size_t gb0 = ((size_t)(bm * 8 + bh) * 16 + tA) * 512 + (size_t)ck * 16;
  const char* const WrB = (const char*)Wr + (size_t)l * 64 * 32768;

  floatx4 acc[4][8];
  #pragma unroll
  for (int i = 0; i < 4; ++i)
    #pragma unroll
    for (int j = 0; j < 8; ++j)
      acc[i][j] = floatx4{0.f, 0.f, 0.f, 0.f};

  for (int m = 0; m <= l; ++m) {
    const char* srcA[4];
    {
      const bool valid = (tA >= m);
      const size_t base = gb0 - (size_t)m * 512;
      #pragma unroll
      for (int it = 0; it < 4; ++it)
        srcA[it] = valid ? (AbfB + base + (size_t)it * 16384) : (zp + ck * 16);
    }
    const int swzA = (lrow - m) & 7;
    for (int db = 0; db < 4; ++db) {
      const int kt = m * 4 + db;
      // stage A: 16 KB (zero rows come from the zero page)
      #pragma unroll
      for (int it = 0; it < 4; ++it)
        gld16(srcA[it] + db * 128, (char*)sm.st.A + ((size_t)(it * 256 + tid)) * 16);
      // stage B: contiguous 32 KB tile (pre-swizzled, linear copy)
      const char* wsrc = WrB + (size_t)kt * 32768;
      #pragma unroll
      for (int it = 0; it < 8; ++it)
        gld16(wsrc + (size_t)(it * 256 + tid) * 16, (char*)sm.st.B + ((size_t)(it * 256 + tid)) * 16);
      __syncthreads();
      #pragma unroll
      for (int ks = 0; ks < 2; ++ks) {
        const int pa = (((ks * 4 + kq) ^ swzA) & 7) * 8;
        const int pb = (((ks * 4 + kq) ^ lrow) & 7) * 8;
        bf16x8 aF[4], bF[8];
        #pragma unroll
        for (int i = 0; i < 4; ++i)
          aF[i] = *(const bf16x8*)&sm.st.A[(wm * 64 + i * 16 + lrow) * 64 + pa];
        #pragma unroll
        for (int j = 0; j < 8; ++j)
          bF[j] = *(const bf16x8*)&sm.st.B[(wn * 128 + j * 16 + lrow) * 64 + pb];
        #pragma unroll
        for (int i = 0; i < 4; ++i)
          #pragma unroll
          for (int j = 0; j < 8; ++j)
            acc[i][j] = __builtin_amdgcn_mfma_f32_16x16x32_bf16(aF[i], bF[j], acc[i][j], 0, 0, 0);
      }
      __syncthreads();
    }
  }

  // ---- epilogue: f = sigmoid(relu(acc + conv_b)) -> bf16 tile in LDS ----
  // C/D layout: col = lane&15, row = (lane>>4)*4 + reg
  #pragma unroll
  for (int j = 0; j < 8; ++j) {
    int col = wn * 128 + j * 16 + lrow;
    float cb = conv_b[l * 256 + col];
    #pragma unroll
    for (int i = 0; i < 4; ++i) {
      #pragma unroll
      for (int r = 0; r < 4; ++r) {
        int row = wm * 64 + i * 16 + kq * 4 + r;
        float x = acc[i][j][r] + cb;
        x = fmaxf(x, 0.f);
        float f = 1.f / (1.f + __expf(-x));
        sm.fT[row * 256 + col] = f2b(f);
      }
    }
  }
  __syncthreads();

  // ---- 3x fo-pooling scan over t, sum over t, accumulate into o[b][c] ----
  #pragma unroll
  for (int q = 0; q < 8; ++q) {
    int p   = q * 256 + tid;       // 2048 (b,c) pairs: 8 b x 256 c
    int c   = p & 255;
    int b_l = p >> 8;
    int b_g = bm * 8 + b_l;
    float xv[16], fv[16];
    #pragma unroll
    for (int t = 0; t < 16; ++t) {
      xv[t] = embf[((size_t)b_g * 16 + t) * 256 + c];
      fv[t] = b2f(sm.fT[(b_l * 16 + t) * 256 + c]);
    }
    #pragma unroll
    for (int pass = 0; pass < 3; ++pass) {
      float h = 0.f;
      #pragma unroll
      for (int t = 0; t < 16; ++t) { h = fv[t] * xv[t] + (1.f - fv[t]) * h; xv[t] = h; }
    }
    float s = 0.f;
    #pragma unroll
    for (int t = 0; t < 16; ++t) s += xv[t];
    atomicAdd(&o[b_g * 256 + c], s);
  }
}

// ---------- head: z = [o, user_emb[user]] @ fc1_w.T + fc1_b; res = z . W2[item] + b2 ----------
__global__ __launch_bounds__(256) void head_kernel(
    const float* __restrict__ o, const float* __restrict__ user_emb,
    const int* __restrict__ user_var, const float* __restrict__ fwT,  // [512][256]
    const float* __restrict__ fc1_b, const float* __restrict__ W2,
    const float* __restrict__ b2, const int* __restrict__ item_var,
    float* __restrict__ out)
{
  __shared__ __align__(16) float cat[512];
  __shared__ __align__(16) float zz[256];
  int b = blockIdx.x;
  int tid = threadIdx.x;
  int uid = user_var[b];
  cat[tid]       = o[b * 256 + tid];
  cat[256 + tid] = user_emb[(size_t)uid * 256 + tid];
  __syncthreads();
  float a = fc1_b[tid];
  #pragma unroll 8
  for (int k = 0; k < 512; ++k)
    a += fwT[(size_t)k * 256 + tid] * cat[k];   // lane-coalesced (transposed weights)
  zz[tid] = a;
  __syncthreads();
  int n = tid >> 3, s = tid & 7;
  int it = item_var[b * 32 + n];
  const float4* w   = (const float4*)(W2 + (size_t)it * 256);
  const float4* zv4 = (const float4*)zz;
  float acc = 0.f;
  #pragma unroll
  for (int i = 0; i < 8; ++i) {
    int k4 = i * 8 + s;
    float4 wv = w[k4];
    float4 zv = zv4[k4];
    acc += wv.x * zv.x + wv.y * zv.y + wv.z * zv.z + wv.w * zv.w;
  }
  acc += __shfl_down(acc, 4, 8);
  acc += __shfl_down(acc, 2, 8);
  acc += __shfl_down(acc, 1, 8);
  if (s == 0) out[b * 32 + n] = acc + b2[it];
}

extern "C" void kernel_launch(void* const* d_in, const int* in_sizes, int n_in,
                              void* d_out, int out_size, void* d_ws, size_t ws_size,
                              hipStream_t stream) {
  (void)in_sizes; (void)n_in; (void)out_size; (void)ws_size;
  const int*   seq_var  = (const int*)d_in[0];
  const int*   user_var = (const int*)d_in[1];
  const int*   item_var = (const int*)d_in[2];
  const float* item_emb = (const float*)d_in[3];
  const float* user_emb = (const float*)d_in[4];
  const float* conv_w   = (const float*)d_in[5];
  const float* conv_b   = (const float*)d_in[6];
  const float* fc1_w    = (const float*)d_in[7];
  const float* fc1_b    = (const float*)d_in[8];
  const float* W2       = (const float*)d_in[9];
  const float* b2       = (const float*)d_in[10];
  float* out = (float*)d_out;

  char* ws = (char*)d_ws;
  unsigned short* cwr = (unsigned short*)ws;                // 33,554,432 B
  unsigned short* ebf = (unsigned short*)(ws + 33554432);   //  4,194,304 B
  float*          ef  = (float*)(ws + 37748736);            //  8,388,608 B
  float*          o   = (float*)(ws + 46137344);            //    524,288 B
  char*           zp  = ws + 46661632;                      //        512 B
  float*          fwT = (float*)(ws + 46662144);            //    524,288 B

  hipMemsetAsync(o, 0, 524288 + 512, stream);   // zeros o and the zero page
  prep_kernel<<<10272, 256, 0, stream>>>(conv_w, cwr, seq_var, item_emb, ef, ebf, fc1_w, fwT);
  conv_qrnn_kernel<<<1024, 256, 0, stream>>>(ebf, cwr, ef, conv_b, zp, o);
  head_kernel<<<512, 256, 0, stream>>>(o, user_emb, user_var, fwT, fc1_b, W2, b2, item_var, out);
}